// Round 1
// baseline (681.233 us; speedup 1.0000x reference)
//
#include <hip/hip_runtime.h>

// GQA forward on MI355X. bf16 MFMA everywhere, f32 accum.
// H=16 heads, G=4 groups, D=2048, HD=128, KV=512, bs=2, s=2048.
// NOTE: reference's _expand_kv is a RAW RESHAPE (scramble), not a transpose:
//   k[b,h,t',d] = Kp[b, h*128 + t'/16, (t'%4)*128 + d]   (same for v)

#define DEV __device__ __forceinline__

typedef float f32x4 __attribute__((ext_vector_type(4)));
typedef __bf16 bf16x8 __attribute__((ext_vector_type(8)));

DEV f32x4 mfma16(bf16x8 a, bf16x8 b, f32x4 c) {
  return __builtin_amdgcn_mfma_f32_16x16x32_bf16(a, b, c, 0, 0, 0);
}

// async global->LDS, 16B per lane. LDS dest = wave-uniform base + lane*16.
DEV void gld16(void* gsrc, void* ldst) {
  __builtin_amdgcn_global_load_lds(
      (__attribute__((address_space(1))) unsigned int*)gsrc,
      (__attribute__((address_space(3))) unsigned int*)ldst, 16, 0, 0);
}

// ---------------- X f32 -> bf16 ----------------
__global__ void convert_f32_bf16(const float* __restrict__ in, __bf16* __restrict__ out) {
  size_t i = ((size_t)blockIdx.x * 256 + threadIdx.x) * 8;
  float4 a = *(const float4*)(in + i);
  float4 b = *(const float4*)(in + i + 4);
  bf16x8 v;
  v[0] = (__bf16)a.x; v[1] = (__bf16)a.y; v[2] = (__bf16)a.z; v[3] = (__bf16)a.w;
  v[4] = (__bf16)b.x; v[5] = (__bf16)b.y; v[6] = (__bf16)b.z; v[7] = (__bf16)b.w;
  *(bf16x8*)(out + i) = v;
}

// ---------------- W [K][N] f32 -> WT [N][K] bf16 ----------------
__global__ void transpose_w_bf16(const float* __restrict__ W, __bf16* __restrict__ WT,
                                 int K, int N) {
  __shared__ float t[32][33];
  int tx = threadIdx.x & 31, ty = threadIdx.x >> 5;  // 32x8
  int n0 = blockIdx.x * 32, k0 = blockIdx.y * 32;
#pragma unroll
  for (int i = 0; i < 4; i++)
    t[ty + i * 8][tx] = W[(size_t)(k0 + ty + i * 8) * N + n0 + tx];
  __syncthreads();
#pragma unroll
  for (int i = 0; i < 4; i++)
    WT[(size_t)(n0 + ty + i * 8) * K + k0 + tx] = (__bf16)t[tx][ty + i * 8];
}

// ---------------- GEMM: C[M][N] = A[M][K] * Bt[N][K]^T + bias, m97 structure ----------------
template <int F32OUT>
__global__ void gemm_bt(const __bf16* __restrict__ A, const __bf16* __restrict__ Bt,
                        const float* __restrict__ bias, float scale, void* __restrict__ Cout,
                        int M, int N, int K) {
  __shared__ __bf16 As[128 * 32];
  __shared__ __bf16 Bs[128 * 32];
  int tid = threadIdx.x, lane = tid & 63, w = tid >> 6;
  int wm = w >> 1, wn = w & 1, lg = lane >> 4, lc = lane & 15;
  int m0 = blockIdx.y * 128, n0 = blockIdx.x * 128;
  int srow = w * 16 + (lane >> 2), scol = (lane & 3) * 8;  // stage: 16B/lane
  const __bf16* Ag = A + (size_t)(m0 + srow) * K + scol;
  const __bf16* Bg = Bt + (size_t)(n0 + srow) * K + scol;
  f32x4 acc[4][4] = {};
  int nk = K >> 5;
  for (int kt = 0; kt < nk; ++kt) {
    if (kt) __syncthreads();
    const __bf16* a = Ag + kt * 32;
    const __bf16* bp = Bg + kt * 32;
    gld16((void*)a, As + (w * 16) * 32);
    gld16((void*)(a + (size_t)64 * K), As + (64 + w * 16) * 32);
    gld16((void*)bp, Bs + (w * 16) * 32);
    gld16((void*)(bp + (size_t)64 * K), Bs + (64 + w * 16) * 32);
    __syncthreads();
    bf16x8 af[4], bf[4];
#pragma unroll
    for (int i = 0; i < 4; i++)
      af[i] = *(const bf16x8*)(As + (wm * 64 + i * 16 + lc) * 32 + lg * 8);
#pragma unroll
    for (int i = 0; i < 4; i++)
      bf[i] = *(const bf16x8*)(Bs + (wn * 64 + i * 16 + lc) * 32 + lg * 8);
#pragma unroll
    for (int mi = 0; mi < 4; mi++)
#pragma unroll
      for (int ni = 0; ni < 4; ni++)
        acc[mi][ni] = mfma16(af[mi], bf[ni], acc[mi][ni]);
  }
  float bcol[4];
#pragma unroll
  for (int ni = 0; ni < 4; ni++) bcol[ni] = bias[n0 + wn * 64 + ni * 16 + lc];
#pragma unroll
  for (int mi = 0; mi < 4; mi++)
#pragma unroll
    for (int ni = 0; ni < 4; ni++)
#pragma unroll
      for (int r = 0; r < 4; r++) {
        int row = m0 + wm * 64 + mi * 16 + lg * 4 + r;
        int col = n0 + wn * 64 + ni * 16 + lc;
        float v = (acc[mi][ni][r] + bcol[ni]) * scale;
        if (F32OUT)
          ((float*)Cout)[(size_t)row * N + col] = v;
        else
          ((__bf16*)Cout)[(size_t)row * N + col] = (__bf16)v;
      }
}

// ---------------- expand/scramble KV ----------------
// Kx[bh][t'][d] = Kp[b*2048 + h*128 + t'/16][(t'%4)*128 + d]
// Vxt[bh][d][t'] = Vp[ same row ][(t'%4)*128 + d]   (transposed for PV B-frags)
__global__ void expand_kv(const __bf16* __restrict__ Kp, const __bf16* __restrict__ Vp,
                          __bf16* __restrict__ Kx, __bf16* __restrict__ Vxt) {
  __shared__ __bf16 Kl[16][512];
  __shared__ __bf16 Vl[16][512];
  int tid = threadIdx.x;
  int bh = blockIdx.x >> 3, tc = blockIdx.x & 7;
  int b = bh >> 4, h = bh & 15;
  size_t srow0 = (size_t)b * 2048 + h * 128 + tc * 16;
#pragma unroll
  for (int it = 0; it < 4; ++it) {
    int idx = it * 256 + tid;
    int rr = idx >> 6, ch = idx & 63;
    *(float4*)(&Kl[rr][ch * 8]) = *(const float4*)(Kp + (srow0 + rr) * 512 + ch * 8);
    *(float4*)(&Vl[rr][ch * 8]) = *(const float4*)(Vp + (srow0 + rr) * 512 + ch * 8);
  }
  __syncthreads();
#pragma unroll
  for (int it = 0; it < 16; ++it) {  // Kx: 256 t' x 128 d
    int idx = it * 256 + tid;
    int tloc = idx >> 4, ch = idx & 15;
    int tp = tc * 256 + tloc, rr = tloc >> 4, g = tloc & 3;
    *(float4*)(Kx + ((size_t)bh * 2048 + tp) * 128 + ch * 8) =
        *(const float4*)(&Kl[rr][g * 128 + ch * 8]);
  }
#pragma unroll
  for (int it = 0; it < 16; ++it) {  // Vxt: 128 d x 256 t'
    int idx = it * 256 + tid;
    int d = idx >> 5, c8 = idx & 31;
    int rr = c8 >> 1;
    bf16x8 v;
#pragma unroll
    for (int j = 0; j < 8; j++) v[j] = Vl[rr][(j & 3) * 128 + d];
    *(bf16x8*)(Vxt + ((size_t)bh * 128 + d) * 2048 + tc * 256 + c8 * 8) = v;
  }
}

// ---------------- flash attention, causal ----------------
// block = 4 waves, QBLK=64 (16 q-rows/wave), KVBLK=64, HD=128.
// Q pre-scaled by log2e/sqrt(128); softmax in exp2 domain.
__global__ void attn_fwd(const __bf16* __restrict__ Qb, const __bf16* __restrict__ Kx,
                         const __bf16* __restrict__ Vxt, __bf16* __restrict__ attO) {
  __shared__ alignas(16) char Ks[64 * 256];    // [t'][256B], 16B blocks XOR-swizzled
  __shared__ alignas(16) char Vts[128 * 128];  // [d][128B]
  __shared__ alignas(16) char Ps[4 * 2048];    // per-wave P [16 q][64 t'] bf16
  int tid = threadIdx.x, lane = tid & 63, w = tid >> 6;
  int lg = lane >> 4, lc = lane & 15;
  int qt = 31 - (int)blockIdx.x;  // heavy blocks first
  int bh = blockIdx.y, b = bh >> 4, h = bh & 15;
  int q0 = qt * 64;
  const __bf16* Qrow = Qb + (size_t)(b * 2048 + q0 + w * 16 + lc) * 2048 + h * 128 + lg * 8;
  bf16x8 qf[4];
#pragma unroll
  for (int ks = 0; ks < 4; ks++) qf[ks] = *(const bf16x8*)(Qrow + ks * 32);
  f32x4 o[8] = {};
  float mrow[4], lrow[4];
#pragma unroll
  for (int r = 0; r < 4; r++) { mrow[r] = -3.0e38f; lrow[r] = 0.f; }
  const __bf16* Kg = Kx + (size_t)bh * 2048 * 128;
  const __bf16* Vg = Vxt + (size_t)bh * 128 * 2048;
  char* Psw = Ps + w * 2048;

  for (int kt = 0; kt <= qt; ++kt) {
    float4 kreg[4], vreg[4];
#pragma unroll
    for (int it = 0; it < 4; it++) {
      int idx = it * 256 + tid, kr = idx >> 4, kc = idx & 15;
      kreg[it] = *(const float4*)(Kg + (size_t)(kt * 64 + kr) * 128 + kc * 8);
    }
#pragma unroll
    for (int it = 0; it < 4; it++) {
      int idx = it * 256 + tid, vr = idx >> 3, vc = idx & 7;
      vreg[it] = *(const float4*)(Vg + (size_t)vr * 2048 + kt * 64 + vc * 8);
    }
    if (kt) __syncthreads();  // prev tile's LDS reads done before overwrite
#pragma unroll
    for (int it = 0; it < 4; it++) {
      int idx = it * 256 + tid, kr = idx >> 4, kc = idx & 15;
      *(float4*)(Ks + kr * 256 + ((kc * 16) ^ ((kr & 7) << 4))) = kreg[it];
    }
#pragma unroll
    for (int it = 0; it < 4; it++) {
      int idx = it * 256 + tid, vr = idx >> 3, vc = idx & 7;
      *(float4*)(Vts + vr * 128 + ((vc * 16) ^ ((vr & 7) << 4))) = vreg[it];
    }
    __syncthreads();

    // QK^T: S[16q][64t']
    f32x4 s[4];
#pragma unroll
    for (int nt = 0; nt < 4; nt++) {
      s[nt] = (f32x4){0.f, 0.f, 0.f, 0.f};
#pragma unroll
      for (int ks = 0; ks < 4; ks++) {
        int trow = nt * 16 + lc;
        bf16x8 kf = *(const bf16x8*)(Ks + trow * 256 + ((ks * 64 + lg * 16) ^ ((trow & 7) << 4)));
        s[nt] = mfma16(qf[ks], kf, s[nt]);
      }
    }
    if (kt == qt) {  // causal mask on diagonal tile
#pragma unroll
      for (int nt = 0; nt < 4; nt++)
#pragma unroll
        for (int r = 0; r < 4; r++)
          if (nt * 16 + lc > w * 16 + lg * 4 + r) s[nt][r] = -3.0e38f;
    }
    // online softmax (rows live on 16-lane groups; reduce via shfl_xor 1,2,4,8)
#pragma unroll
    for (int r = 0; r < 4; r++) {
      float v = fmaxf(fmaxf(s[0][r], s[1][r]), fmaxf(s[2][r], s[3][r]));
      v = fmaxf(v, __shfl_xor(v, 1));
      v = fmaxf(v, __shfl_xor(v, 2));
      v = fmaxf(v, __shfl_xor(v, 4));
      v = fmaxf(v, __shfl_xor(v, 8));
      float mn = fmaxf(mrow[r], v);
      float sc = exp2f(mrow[r] - mn);
      mrow[r] = mn;
      lrow[r] *= sc;
#pragma unroll
      for (int dt = 0; dt < 8; dt++) o[dt][r] *= sc;
      float rs = 0.f;
#pragma unroll
      for (int nt = 0; nt < 4; nt++) {
        float p = exp2f(s[nt][r] - mn);
        s[nt][r] = p;
        rs += p;
      }
      rs += __shfl_xor(rs, 1);
      rs += __shfl_xor(rs, 2);
      rs += __shfl_xor(rs, 4);
      rs += __shfl_xor(rs, 8);
      lrow[r] += rs;
    }
    // P (C-layout) -> per-wave LDS, bf16, swizzled; then consumed as A-frags
#pragma unroll
    for (int nt = 0; nt < 4; nt++)
#pragma unroll
      for (int r = 0; r < 4; r++) {
        int row = lg * 4 + r, col = nt * 16 + lc;
        *(__bf16*)(Psw + row * 128 + ((((col >> 3) << 4) ^ ((row & 7) << 4)) | ((col & 7) << 1))) =
            (__bf16)s[nt][r];
      }
    asm volatile("" ::: "memory");  // keep P-writes before PV reads (TBAA guard)
    // PV: o[16q][128d] += P[16q][64t'] * Vt
#pragma unroll
    for (int dt = 0; dt < 8; dt++) {
#pragma unroll
      for (int ks = 0; ks < 2; ks++) {
        bf16x8 af = *(const bf16x8*)(Psw + lc * 128 + ((ks * 64 + lg * 16) ^ ((lc & 7) << 4)));
        int vrow = dt * 16 + lc;
        bf16x8 vf = *(const bf16x8*)(Vts + vrow * 128 + ((ks * 64 + lg * 16) ^ ((vrow & 7) << 4)));
        o[dt] = mfma16(af, vf, o[dt]);
      }
    }
  }
  // epilogue: divide by l, store bf16 to attO[b*2048+q][h*128+d]
#pragma unroll
  for (int r = 0; r < 4; r++) {
    float inv = 1.0f / lrow[r];
    int row = b * 2048 + q0 + w * 16 + lg * 4 + r;
#pragma unroll
    for (int dt = 0; dt < 8; dt++)
      attO[(size_t)row * 2048 + h * 128 + dt * 16 + lc] = (__bf16)(o[dt][r] * inv);
  }
}

extern "C" void kernel_launch(void* const* d_in, const int* in_sizes, int n_in,
                              void* d_out, int out_size, void* d_ws, size_t ws_size,
                              hipStream_t stream) {
  const float* X = (const float*)d_in[0];
  const float* Wq = (const float*)d_in[1];
  const float* bq = (const float*)d_in[2];
  const float* Wk = (const float*)d_in[3];
  const float* bk = (const float*)d_in[4];
  const float* Wv = (const float*)d_in[5];
  const float* bv = (const float*)d_in[6];
  const float* Wo = (const float*)d_in[7];
  const float* bo = (const float*)d_in[8];
  char* ws = (char*)d_ws;
  const size_t MB = 1024 * 1024;
  __bf16* Xb  = (__bf16*)(ws + 0);        // 16 MB
  __bf16* WqT = (__bf16*)(ws + 16 * MB);  // 8 MB
  __bf16* WkT = (__bf16*)(ws + 24 * MB);  // 2 MB
  __bf16* WvT = (__bf16*)(ws + 27 * MB);  // 2 MB
  __bf16* WoT = (__bf16*)(ws + 30 * MB);  // 8 MB
  __bf16* Qbf = (__bf16*)(ws + 38 * MB);  // 16 MB
  __bf16* Kp  = (__bf16*)(ws + 54 * MB);  // 4 MB
  __bf16* Vp  = (__bf16*)(ws + 58 * MB);  // 4 MB
  __bf16* Kx  = (__bf16*)(ws + 62 * MB);  // 16 MB
  __bf16* Vxt = (__bf16*)(ws + 78 * MB);  // 16 MB
  __bf16* aO  = (__bf16*)(ws + 94 * MB);  // 16 MB -> 110 MB total

  convert_f32_bf16<<<4096, 256, 0, stream>>>(X, Xb);
  transpose_w_bf16<<<dim3(64, 64), 256, 0, stream>>>(Wq, WqT, 2048, 2048);
  transpose_w_bf16<<<dim3(16, 64), 256, 0, stream>>>(Wk, WkT, 2048, 512);
  transpose_w_bf16<<<dim3(16, 64), 256, 0, stream>>>(Wv, WvT, 2048, 512);
  transpose_w_bf16<<<dim3(64, 64), 256, 0, stream>>>(Wo, WoT, 2048, 2048);

  // fold 1/sqrt(HD) * log2(e) into Q so softmax uses exp2 directly
  float qscale = 1.4426950408889634f * 0.08838834764831845f;
  gemm_bt<0><<<dim3(16, 32), 256, 0, stream>>>(Xb, WqT, bq, qscale, Qbf, 4096, 2048, 2048);
  gemm_bt<0><<<dim3(4, 32), 256, 0, stream>>>(Xb, WkT, bk, 1.0f, Kp, 4096, 512, 2048);
  gemm_bt<0><<<dim3(4, 32), 256, 0, stream>>>(Xb, WvT, bv, 1.0f, Vp, 4096, 512, 2048);

  expand_kv<<<256, 256, 0, stream>>>(Kp, Vp, Kx, Vxt);
  attn_fwd<<<dim3(32, 32), 256, 0, stream>>>(Qbf, Kx, Vxt, aO);

  gemm_bt<1><<<dim3(16, 32), 256, 0, stream>>>(aO, WoT, bo, 1.0f, (float*)d_out, 4096, 2048, 2048);
}